// Round 4
// baseline (775.974 us; speedup 1.0000x reference)
//
#include <hip/hip_runtime.h>

#define GH 14
#define GW 14
#define GSAMP (GH * GW)     // 196 samples per box
#define PASS_S 28           // samples staged per pass (7 passes x 28 = 196)
#define STG_STRIDE 260      // floats; 16B-aligned rows, conflict-free b128 writes

// ---------------- kernel 1: NCHW -> NHWC transpose (per batch [C,HW] -> [HW,C]) ----
__global__ __launch_bounds__(256) void nchw_to_nhwc_kernel(
    const float* __restrict__ src, float* __restrict__ dst, int C, int HW)
{
    __shared__ float tile[32][33];
    const int b  = blockIdx.z;
    const int p0 = blockIdx.x * 32;
    const int c0 = blockIdx.y * 32;
    const int tx = threadIdx.x;                  // 0..31
    const int ty = threadIdx.y;                  // 0..7
    const float* s = src + (size_t)b * C * HW;
    float*       d = dst + (size_t)b * C * HW;
    #pragma unroll
    for (int k = 0; k < 4; ++k)
        tile[ty + k * 8][tx] = s[(size_t)(c0 + ty + k * 8) * HW + p0 + tx];
    __syncthreads();
    #pragma unroll
    for (int k = 0; k < 4; ++k)
        d[(size_t)(p0 + ty + k * 8) * C + c0 + tx] = tile[tx][ty + k * 8];
}

// ---------------- kernel 2: one block per box; float4 gather over all 256 ch ------
__global__ __launch_bounds__(256, 4) void roi_gather_nhwc_kernel(
    const float* __restrict__ fmapT,   // [N, H, W, C]
    const float* __restrict__ rois,
    const int*   __restrict__ imgh,
    float*       __restrict__ out,     // [M, C, GH, GW]
    int C, int H, int W)
{
    __shared__ int4   s_oq[GSAMP];               // per-sample float4-offsets of 4 corners
    __shared__ float4 s_w[GSAMP];                // per-sample bilinear weights (mask folded)
    __shared__ float  stage[PASS_S * STG_STRIDE];// [28][260]: stage[s][ch]

    const int tid  = threadIdx.x;
    const int lane = tid & 63;
    const int wv   = tid >> 6;                   // wave 0..3
    const int m    = blockIdx.x;

    const float stride = (float)imgh[0] / (float)H;
    const float* r = rois + (size_t)m * 6;
    const int   b   = (int)r[0];
    const float rx1 = r[2] / stride;
    const float ry1 = r[3] / stride;
    const float rx2 = r[4] / stride;
    const float ry2 = r[5] / stride;

    const int C4 = C >> 2;                       // 64 float4 per pixel
    const float fH = (float)(H - 1), fW = (float)(W - 1);

    // ---- phase 0: per-sample setup, computed once per block -------------------
    if (tid < GSAMP) {
        const int i = tid / GW;
        const int j = tid - i * GW;
        const float ys = ry1 + (ry2 - ry1) * ((float)i / (float)(GH - 1));
        const float xs = rx1 + (rx2 - rx1) * ((float)j / (float)(GW - 1));
        const bool my = (ys >= 0.0f) && (ys <= fH);
        const bool mx = (xs >= 0.0f) && (xs <= fW);
        const float y0f = floorf(ys);
        const float x0f = floorf(xs);
        const float ly  = ys - y0f;
        const float lx  = xs - x0f;
        const int y0  = (int)fminf(fmaxf(y0f,        0.0f), fH);
        const int y1i = (int)fminf(fmaxf(y0f + 1.0f, 0.0f), fH);
        const int x0  = (int)fminf(fmaxf(x0f,        0.0f), fW);
        const int x1i = (int)fminf(fmaxf(x0f + 1.0f, 0.0f), fW);
        const float msk = (my && mx) ? 1.0f : 0.0f;
        s_w[tid]  = make_float4(msk * (1.0f - ly) * (1.0f - lx),
                                msk * (1.0f - ly) * lx,
                                msk * ly * (1.0f - lx),
                                msk * ly * lx);
        s_oq[tid] = make_int4((y0  * W + x0 ) * C4,
                              (y0  * W + x1i) * C4,
                              (y1i * W + x0 ) * C4,
                              (y1i * W + x1i) * C4);
    }
    __syncthreads();

    // per-lane base: lane indexes the float4 (= 4 channels) within a pixel
    const float4* __restrict__ bp =
        (const float4*)fmapT + (size_t)b * (size_t)(H * W) * C4 + lane;

    // ---- 7 passes of 28 samples: gather -> LDS -> coalesced dwordx4 writeout --
    for (int pass = 0; pass < GSAMP / PASS_S; ++pass) {
        #pragma unroll 2
        for (int q = 0; q < PASS_S / 4; ++q) {   // each wave: 7 samples per pass
            const int sl = wv * (PASS_S / 4) + q;         // 0..27 within pass
            const int sg = pass * PASS_S + sl;            // global sample index
            const int4   oq = s_oq[sg];                   // broadcast ds_read_b128
            const float4 w  = s_w[sg];
            const float4 g00 = bp[oq.x];
            const float4 g01 = bp[oq.y];
            const float4 g10 = bp[oq.z];
            const float4 g11 = bp[oq.w];
            float4 acc;
            acc.x = g00.x * w.x + g01.x * w.y + g10.x * w.z + g11.x * w.w;
            acc.y = g00.y * w.x + g01.y * w.y + g10.y * w.z + g11.y * w.w;
            acc.z = g00.z * w.x + g01.z * w.y + g10.z * w.z + g11.z * w.w;
            acc.w = g00.w * w.x + g01.w * w.y + g10.w * w.z + g11.w * w.w;
            // conflict-free b128 write: 16B lane stride, row stride 1040B
            *(float4*)&stage[sl * STG_STRIDE + 4 * lane] = acc;
        }
        __syncthreads();

        // writeout: 256 ch x 7 quad-groups = 1792 dwordx4 stores, 7 per thread
        #pragma unroll
        for (int it = 0; it < 7; ++it) {
            const int e4 = tid + 256 * it;       // < 1792
            const int ch = e4 / 7;
            const int sq = e4 - 7 * ch;          // quad-group within pass
            float4 v;
            v.x = stage[(4 * sq + 0) * STG_STRIDE + ch];
            v.y = stage[(4 * sq + 1) * STG_STRIDE + ch];
            v.z = stage[(4 * sq + 2) * STG_STRIDE + ch];
            v.w = stage[(4 * sq + 3) * STG_STRIDE + ch];
            *(float4*)(out + ((size_t)m * C + ch) * GSAMP + pass * PASS_S + 4 * sq) = v;
        }
        __syncthreads();
    }
}

// ---------------- fallback (workspace too small): round-1 kernel ------------------
#define CCHUNK 64
__global__ __launch_bounds__(256) void roi_align_fallback(
    const float* __restrict__ fmap, const float* __restrict__ rois,
    const int* __restrict__ imgh, float* __restrict__ out, int C, int H, int W)
{
    const int t = threadIdx.x;
    if (t >= GH * GW) return;
    const int m = blockIdx.y;
    const int c0 = blockIdx.x * CCHUNK;
    const int j = t % GW;
    const int i = t / GW;
    const float stride = (float)imgh[0] / (float)H;
    const float* r = rois + (size_t)m * 6;
    const int b = (int)r[0];
    const float x1 = r[2] / stride, y1 = r[3] / stride;
    const float x2 = r[4] / stride, y2 = r[5] / stride;
    const float ys = y1 + (y2 - y1) * ((float)i / (float)(GH - 1));
    const float xs = x1 + (x2 - x1) * ((float)j / (float)(GW - 1));
    const bool my = (ys >= 0.0f) && (ys <= (float)(H - 1));
    const bool mx = (xs >= 0.0f) && (xs <= (float)(W - 1));
    const float y0f = floorf(ys), x0f = floorf(xs);
    const float ly = ys - y0f, lx = xs - x0f;
    const int y0  = (int)fminf(fmaxf(y0f,        0.0f), (float)(H - 1));
    const int y1i = (int)fminf(fmaxf(y0f + 1.0f, 0.0f), (float)(H - 1));
    const int x0  = (int)fminf(fmaxf(x0f,        0.0f), (float)(W - 1));
    const int x1i = (int)fminf(fmaxf(x0f + 1.0f, 0.0f), (float)(W - 1));
    const float msk = (my && mx) ? 1.0f : 0.0f;
    const float w00 = msk * (1.0f - ly) * (1.0f - lx);
    const float w01 = msk * (1.0f - ly) * lx;
    const float w10 = msk * ly * (1.0f - lx);
    const float w11 = msk * ly * lx;
    const int o00 = y0 * W + x0, o01 = y0 * W + x1i;
    const int o10 = y1i * W + x0, o11 = y1i * W + x1i;
    const int HW = H * W;
    const float* __restrict__ p = fmap + ((size_t)b * C + c0) * (size_t)HW;
    float* __restrict__ o = out + ((size_t)m * C + c0) * (size_t)(GH * GW) + t;
    #pragma unroll 4
    for (int c = 0; c < CCHUNK; ++c) {
        const float g00 = p[o00], g01 = p[o01], g10 = p[o10], g11 = p[o11];
        *o = g00 * w00 + g01 * w01 + g10 * w10 + g11 * w11;
        p += HW; o += GH * GW;
    }
}

extern "C" void kernel_launch(void* const* d_in, const int* in_sizes, int n_in,
                              void* d_out, int out_size, void* d_ws, size_t ws_size,
                              hipStream_t stream) {
    const float* fmap = (const float*)d_in[0];   // [4, 256, 200, 200]
    const float* rois = (const float*)d_in[1];   // [M, 6]
    const int*   imgh = (const int*)d_in[2];     // scalar 800
    float* out = (float*)d_out;

    const int C = 256, H = 200, W = 200, N = 4;
    const int M  = in_sizes[1] / 6;              // 2048
    const int HW = H * W;

    const size_t need = (size_t)N * C * HW * sizeof(float);  // 163.84 MB
    if (ws_size >= need) {
        float* fmapT = (float*)d_ws;
        dim3 tgrid(HW / 32, C / 32, N);
        nchw_to_nhwc_kernel<<<tgrid, dim3(32, 8), 0, stream>>>(fmap, fmapT, C, HW);
        roi_gather_nhwc_kernel<<<dim3(M), 256, 0, stream>>>(fmapT, rois, imgh, out, C, H, W);
    } else {
        dim3 grid(C / CCHUNK, M);
        roi_align_fallback<<<grid, 256, 0, stream>>>(fmap, rois, imgh, out, C, H, W);
    }
}